// Round 5
// baseline (1039.722 us; speedup 1.0000x reference)
//
#include <hip/hip_runtime.h>
#include <math.h>

// GCN on MI355X. N=200000 nodes, E=6400000 edges.
// R19: k_part was the #1 dispatch (87.5us) with NOTHING saturated (HBM 9%,
// VALU 5%, Occ 54%): a latency/serialization machine -- per-edge LDS atomic
// with return dependency, barrier+flush bookkeeping, 51.7KB LDS -> 3 blk/CU.
// The R18 phased gathers only need dst-grouping + 4-way src-quarter grouping,
// i.e. a counting sort on key dst*4 + src/50000 (800K counters, ~8 edges
// each -> negligible atomic contention). New build: k_hist (fire-and-forget
// global atomics) -> 3-kernel scan over 3.2MB -> k_scatter (cursor atomic +
// 4B store). ebase[4i..4i+4] serves as rowptr AND phase boundaries. Deletes
// k_part / k_scan_sub / k_build entirely (~110us -> ~50us predicted).
// adj reads in gathers are nontemporal (streaming; protects the L2 slab).
// Gather structure (R18 phases, R17 packed rows/slot-stride) unchanged.
// MESSAGES STAY FP32 (R7: bf16 fails 0.21).

static constexpr int NN = 200000;
static constexpr int NE = 6400000;
static constexpr int BK = 256;

static constexpr int QDIV = NN / 4;                  // 50000: src-quarter divisor
static constexpr int SCT  = 4096;                    // scan tile (256 thr x 16)

static constexpr int S    = 4;                       // lanes per node in gathers
static constexpr int LOGS = 2;

// ---------- build pass 1: histogram of (dst, src-quarter) ----------
__global__ void __launch_bounds__(256) k_hist(const int* __restrict__ srcI,
                                              const int* __restrict__ dstI,
                                              int* __restrict__ cnt, int e) {
  int T = gridDim.x * blockDim.x;
  int i0 = blockIdx.x * blockDim.x + threadIdx.x;
#pragma unroll
  for (int u = 0; u < 8; ++u) {
    int i = i0 + u * T;
    if (i < e) {
      int s = __builtin_nontemporal_load(srcI + i);
      int d = __builtin_nontemporal_load(dstI + i);
      int qp = (int)((unsigned)s / (unsigned)QDIV);
      atomicAdd(&cnt[4 * d + qp], 1);                // no return use: fire-and-forget
    }
  }
}

// ---------- build pass 2a: per-tile sums ----------
__global__ void __launch_bounds__(256) k_scan1(const int* __restrict__ cnt,
                                               int* __restrict__ bsum, int M) {
  __shared__ int red[256];
  int b = blockIdx.x, t = threadIdx.x;
  int base = b * SCT + t * 16;
  int s = 0;
  if (base + 16 <= M) {
    const uint4* p = (const uint4*)(cnt + base);
#pragma unroll
    for (int j = 0; j < 4; ++j) { uint4 v = p[j]; s += (int)(v.x + v.y + v.z + v.w); }
  } else {
    for (int j = 0; j < 16; ++j) if (base + j < M) s += cnt[base + j];
  }
  red[t] = s;
  __syncthreads();
  for (int o = 128; o > 0; o >>= 1) {
    if (t < o) red[t] += red[t + o];
    __syncthreads();
  }
  if (t == 0) bsum[b] = red[0];
}

// ---------- build pass 2b: exclusive scan of tile sums (nbl <= 256) ----------
__global__ void k_scan2(int* __restrict__ bsum, int* __restrict__ ebase,
                        int nbl, int M) {
  __shared__ int s0[256], s1[256];
  int t = threadIdx.x;
  int v = (t < nbl) ? bsum[t] : 0;
  s0[t] = v;
  __syncthreads();
  int* a = s0; int* b = s1;
  for (int o = 1; o < 256; o <<= 1) {
    b[t] = a[t] + ((t >= o) ? a[t - o] : 0);
    __syncthreads();
    int* tmp = a; a = b; b = tmp;
  }
  if (t < nbl) bsum[t] = a[t] - v;        // exclusive
  if (t == nbl - 1) ebase[M] = a[t];      // total == E (rowptr[N])
}

// ---------- build pass 2c: local exclusive scan + offset -> ebase, cursor ----------
__global__ void __launch_bounds__(256) k_scan3(const int* __restrict__ cnt,
                                               const int* __restrict__ bsum,
                                               int* __restrict__ ebase,
                                               int* __restrict__ cursor, int M) {
  __shared__ int s0[256], s1[256];
  int b = blockIdx.x, t = threadIdx.x;
  int base = b * SCT + t * 16;
  int loc[16];
  int s = 0;
  if (base + 16 <= M) {
    const uint4* p = (const uint4*)(cnt + base);
#pragma unroll
    for (int j = 0; j < 4; ++j) {
      uint4 v = p[j];
      loc[4 * j]     = s; s += (int)v.x;
      loc[4 * j + 1] = s; s += (int)v.y;
      loc[4 * j + 2] = s; s += (int)v.z;
      loc[4 * j + 3] = s; s += (int)v.w;
    }
  } else {
    for (int j = 0; j < 16; ++j) {
      loc[j] = s;
      if (base + j < M) s += cnt[base + j];
    }
  }
  s0[t] = s;
  __syncthreads();
  int* a = s0; int* bb = s1;
  for (int o = 1; o < 256; o <<= 1) {
    bb[t] = a[t] + ((t >= o) ? a[t - o] : 0);
    __syncthreads();
    int* tmp = a; a = bb; bb = tmp;
  }
  int off = bsum[b] + a[t] - s;           // exclusive across grid
  if (base + 16 <= M) {
    uint4* pe = (uint4*)(ebase + base);
    uint4* pc = (uint4*)(cursor + base);
#pragma unroll
    for (int j = 0; j < 4; ++j) {
      uint4 v;
      v.x = (unsigned)(off + loc[4 * j]);
      v.y = (unsigned)(off + loc[4 * j + 1]);
      v.z = (unsigned)(off + loc[4 * j + 2]);
      v.w = (unsigned)(off + loc[4 * j + 3]);
      pe[j] = v; pc[j] = v;
    }
  } else {
    for (int j = 0; j < 16; ++j) {
      if (base + j < M) {
        ebase[base + j] = off + loc[j];
        cursor[base + j] = off + loc[j];
      }
    }
  }
}

// ---------- build pass 3: direct scatter into (dst, quarter)-grouped adj ----------
__global__ void __launch_bounds__(256) k_scatter(const int* __restrict__ srcI,
                                                 const int* __restrict__ dstI,
                                                 int* __restrict__ cursor,
                                                 int* __restrict__ adj, int e) {
  int T = gridDim.x * blockDim.x;
  int i0 = blockIdx.x * blockDim.x + threadIdx.x;
#pragma unroll
  for (int u = 0; u < 8; ++u) {
    int i = i0 + u * T;
    if (i < e) {
      int s = __builtin_nontemporal_load(srcI + i);
      int d = __builtin_nontemporal_load(dstI + i);
      int qp = (int)((unsigned)s / (unsigned)QDIV);
      int pos = atomicAdd(&cursor[4 * d + qp], 1);
      adj[pos] = s;                       // within-quarter order = arrival (sum ok)
    }
  }
}

__global__ void k_zero(int* __restrict__ p, int n) {
  int i = blockIdx.x * blockDim.x + threadIdx.x;
  if (i < n) p[i] = 0;
}

// deg = ebase[4i+4] - ebase[4i] (dense counting-sort packing)
__global__ void k_dinv(const int* __restrict__ eb, float* __restrict__ dinv, int n) {
  int i = blockIdx.x * blockDim.x + threadIdx.x;
  if (i < n) dinv[i] = rsqrtf(1.0f + (float)(eb[4 * i + 4] - eb[4 * i]));
}

// p1[i] = dinv[i] * x[i]  (3 floats, packed 12B rows)
__global__ void k_prep(const float* __restrict__ x, const float* __restrict__ dinv,
                       float* __restrict__ p1, int n) {
  int i = blockIdx.x * blockDim.x + threadIdx.x;
  if (i >= n) return;
  float di = dinv[i];
  float3 v;
  v.x = di * x[3 * (size_t)i];
  v.y = di * x[3 * (size_t)i + 1];
  v.z = di * x[3 * (size_t)i + 2];
  *(float3*)(p1 + 3 * (size_t)i) = v;
}

// ---------- packed-row load/accumulate/store (RW floats per row) ----------
template <int RW> struct RowT;
template <> struct RowT<3> {
  using T = float3;   // 12B rows
  static __device__ inline T ld(const float* __restrict__ p) { return *(const float3*)p; }
  static __device__ inline void add(float* __restrict__ a, const T& v) {
    a[0] += v.x; a[1] += v.y; a[2] += v.z;
  }
  static __device__ inline void st(float* __restrict__ p, const float* __restrict__ a) {
    *(float3*)p = make_float3(a[0], a[1], a[2]);
  }
};
template <> struct RowT<6> {
  struct T { float2 a, b, c; };       // 24B rows, 8B-aligned
  static __device__ inline T ld(const float* __restrict__ p) {
    T t; t.a = *(const float2*)p; t.b = *(const float2*)(p + 2); t.c = *(const float2*)(p + 4);
    return t;
  }
  static __device__ inline void add(float* __restrict__ a, const T& v) {
    a[0] += v.a.x; a[1] += v.a.y; a[2] += v.b.x; a[3] += v.b.y; a[4] += v.c.x; a[5] += v.c.y;
  }
  static __device__ inline void st(float* __restrict__ p, const float* __restrict__ a) {
    *(float2*)(p)     = make_float2(a[0], a[1]);
    *(float2*)(p + 2) = make_float2(a[2], a[3]);
    *(float2*)(p + 4) = make_float2(a[4], a[5]);
  }
};
template <> struct RowT<12> {
  struct T { float4 a, b, c; };       // 48B rows, 16B-aligned bases
  static __device__ inline T ld(const float* __restrict__ p) {
    T t; t.a = *(const float4*)p; t.b = *(const float4*)(p + 4); t.c = *(const float4*)(p + 8);
    return t;
  }
  static __device__ inline void add(float* __restrict__ a, const T& v) {
    a[0] += v.a.x; a[1] += v.a.y; a[2] += v.a.z; a[3] += v.a.w;
    a[4] += v.b.x; a[5] += v.b.y; a[6] += v.b.z; a[7] += v.b.w;
    a[8] += v.c.x; a[9] += v.c.y; a[10] += v.c.z; a[11] += v.c.w;
  }
  static __device__ inline void st(float* __restrict__ p, const float* __restrict__ a) {
    *(float4*)(p)     = make_float4(a[0], a[1], a[2], a[3]);
    *(float4*)(p + 4) = make_float4(a[4], a[5], a[6], a[7]);
    *(float4*)(p + 8) = make_float4(a[8], a[9], a[10], a[11]);
  }
};

// ---------- slot-strided gather over [st,en), unroll UN, adj prefetch 1 ahead ----------
// adj loads are nontemporal: pure streaming, keeps the p-slab resident in L2.
template <int RW, int UN>
__device__ inline void gather_p(const int* __restrict__ adj, int st, int en,
                                const float* __restrict__ pin, float* __restrict__ acc,
                                int slot) {
  using RT = RowT<RW>;
  using T = typename RT::T;
  int k = st + slot;
  if (k + (UN - 1) * S < en) {
    int a[UN];
#pragma unroll
    for (int u = 0; u < UN; ++u) a[u] = __builtin_nontemporal_load(adj + k + u * S);
    for (;;) {
      int kn = k + UN * S;
      bool more = (kn + (UN - 1) * S < en);
      int b[UN];
#pragma unroll
      for (int u = 0; u < UN; ++u) b[u] = 0;
      if (more) {
#pragma unroll
        for (int u = 0; u < UN; ++u) b[u] = __builtin_nontemporal_load(adj + kn + u * S);
      }
      T v[UN];
#pragma unroll
      for (int u = 0; u < UN; ++u) v[u] = RT::ld(pin + (size_t)a[u] * RW);
#pragma unroll
      for (int u = 0; u < UN; ++u) RT::add(acc, v[u]);
      k = kn;
      if (!more) break;
#pragma unroll
      for (int u = 0; u < UN; ++u) a[u] = b[u];
    }
  }
  for (; k < en; k += S) {
    T v = RT::ld(pin + (size_t)__builtin_nontemporal_load(adj + k) * RW);
    RT::add(acc, v);
  }
}

// 4-lane butterfly: all lanes end with the full sum
template <int FIN>
__device__ inline void group_reduce(float* __restrict__ acc) {
#pragma unroll
  for (int j = 0; j < FIN; ++j) {
    acc[j] += __shfl_xor(acc[j], 1);
    acc[j] += __shfl_xor(acc[j], 2);
  }
}

// ---------- single-phase fused gather (layer 1 only; slab fits L2) ----------
template <int RW, int FOUT, int MODE>
__global__ void __launch_bounds__(BK, 8) k_gather_fused(
    const int* __restrict__ adj, const int* __restrict__ eb,
    const float* __restrict__ pin, const float* __restrict__ W,
    const float* __restrict__ bias, const float* __restrict__ dinv,
    float* __restrict__ pout, int n) {
  __shared__ float sW[RW * FOUT];
  __shared__ float sb[FOUT];
  for (int t = threadIdx.x; t < RW * FOUT; t += BK) sW[t] = W[t];
  if (threadIdx.x < FOUT) sb[threadIdx.x] = bias[threadIdx.x];
  __syncthreads();
  int g = blockIdx.x * blockDim.x + threadIdx.x;
  int i = g >> LOGS;
  int slot = g & (S - 1);
  if (i >= n) return;
  float acc[RW] = {};
  if (slot == 0) {                                  // self-loop on slot 0
    typename RowT<RW>::T v = RowT<RW>::ld(pin + (size_t)i * RW);
    RowT<RW>::add(acc, v);
  }
  gather_p<RW, 4>(adj, eb[4 * i], eb[4 * i + 4], pin, acc, slot);
  group_reduce<RW>(acc);
  float di = dinv[i];
  float h[FOUT];
  float ss = 0.f;
#pragma unroll
  for (int j = 0; j < FOUT; ++j) {
    float s = 0.f;
#pragma unroll
    for (int kk = 0; kk < RW; ++kk) s = fmaf(acc[kk], sW[kk * FOUT + j], s);
    float t = fmaf(di, s, sb[j]);
    h[j] = t;
    ss += t * t;
  }
  float o[FOUT];
  if (MODE == 0) {
#pragma unroll
    for (int j = 0; j < FOUT; ++j) o[j] = di * tanhf(h[j]);
  } else {
    float inv = 1.f / fmaxf(sqrtf(ss), 1e-12f);
#pragma unroll
    for (int j = 0; j < FOUT; ++j) o[j] = di * tanhf(h[j] * inv);
  }
  if (slot == 0) {
    float* po = pout + (size_t)i * FOUT;
    if (MODE == 0) {                                 // 24B rows: 3x float2
      *(float2*)(po)     = make_float2(o[0], o[1]);
      *(float2*)(po + 2) = make_float2(o[2], o[3]);
      *(float2*)(po + 4) = make_float2(o[4], o[5]);
    } else {                                         // 48B rows: 3x float4
      *(float4*)(po)     = make_float4(o[0], o[1], o[2], o[3]);
      *(float4*)(po + 4) = make_float4(o[4], o[5], o[6], o[7]);
      *(float4*)(po + 8) = make_float4(o[8], o[9], o[10], o[11]);
    }
  }
}

// ---------- phased gather: src-quarter range [OA,OB) per launch ----------
// FIRST: acc = self-loop; else acc = reload packed partial (slot 0 holds it).
template <int RW, bool FIRST, int OA, int OB>
__global__ void __launch_bounds__(BK, 8) k_gphase(
    const int* __restrict__ adj, const int* __restrict__ eb,
    const float* __restrict__ pin, float* __restrict__ accb, int n) {
  int g = blockIdx.x * blockDim.x + threadIdx.x;
  int i = g >> LOGS;
  int slot = g & (S - 1);
  if (i >= n) return;
  float acc[RW] = {};
  if (slot == 0) {
    if (FIRST) {
      typename RowT<RW>::T v = RowT<RW>::ld(pin + (size_t)i * RW);  // self-loop
      RowT<RW>::add(acc, v);
    } else {
      typename RowT<RW>::T v = RowT<RW>::ld(accb + (size_t)i * RW); // partial
      RowT<RW>::add(acc, v);
    }
  }
  gather_p<RW, 2>(adj, eb[4 * i + OA], eb[4 * i + OB], pin, acc, slot);
  group_reduce<RW>(acc);
  if (slot == 0) RowT<RW>::st(accb + (size_t)i * RW, acc);
}

// ---------- final phase: last quarter [OA, 4) + epilogue ----------
// MODE 1: l2norm+tanh -> pout (48B rows for FOUT=12)
// MODE 2: l2norm -> Wc -> l2norm -> out (13 floats)
template <int RW, int FOUT, int MODE, int OA>
__global__ void __launch_bounds__(BK, 6) k_gphase_last(
    const int* __restrict__ adj, const int* __restrict__ eb,
    const float* __restrict__ pin, const float* __restrict__ W,
    const float* __restrict__ bias, const float* __restrict__ Wc,
    const float* __restrict__ bc, const float* __restrict__ dinv,
    const float* __restrict__ accb, float* __restrict__ out, int n) {
  constexpr int FC = 13;
  __shared__ float sW[RW * FOUT];
  __shared__ float sb[FOUT];
  __shared__ float sWc[MODE == 2 ? FOUT * FC : 1];
  __shared__ float sbc[MODE == 2 ? FC : 1];
  for (int t = threadIdx.x; t < RW * FOUT; t += BK) sW[t] = W[t];
  if (threadIdx.x < FOUT) sb[threadIdx.x] = bias[threadIdx.x];
  if (MODE == 2) {
    for (int t = threadIdx.x; t < FOUT * FC; t += BK) sWc[t] = Wc[t];
    if (threadIdx.x < FC) sbc[threadIdx.x] = bc[threadIdx.x];
  }
  __syncthreads();
  int g = blockIdx.x * blockDim.x + threadIdx.x;
  int i = g >> LOGS;
  int slot = g & (S - 1);
  if (i >= n) return;
  float acc[RW] = {};
  if (slot == 0) {
    typename RowT<RW>::T v = RowT<RW>::ld(accb + (size_t)i * RW);   // partial
    RowT<RW>::add(acc, v);
  }
  gather_p<RW, 2>(adj, eb[4 * i + OA], eb[4 * i + 4], pin, acc, slot);
  group_reduce<RW>(acc);
  float di = dinv[i];
  float h[FOUT];
  float ss = 0.f;
#pragma unroll
  for (int j = 0; j < FOUT; ++j) {
    float s = 0.f;
#pragma unroll
    for (int kk = 0; kk < RW; ++kk) s = fmaf(acc[kk], sW[kk * FOUT + j], s);
    float t = fmaf(di, s, sb[j]);
    h[j] = t;
    ss += t * t;
  }
  float inv = 1.f / fmaxf(sqrtf(ss), 1e-12f);
  if (MODE == 1) {
    float o[FOUT];
#pragma unroll
    for (int j = 0; j < FOUT; ++j) o[j] = di * tanhf(h[j] * inv);
    if (slot == 0) {
      float* po = out + (size_t)i * FOUT;                  // 48B rows (FOUT=12)
      *(float4*)(po)     = make_float4(o[0], o[1], o[2], o[3]);
      *(float4*)(po + 4) = make_float4(o[4], o[5], o[6], o[7]);
      *(float4*)(po + 8) = make_float4(o[8], o[9], o[10], o[11]);
    }
  } else {
    float v[FC];
    float ss2 = 0.f;
#pragma unroll
    for (int j = 0; j < FC; ++j) {
      float s = sbc[j];
#pragma unroll
      for (int kk = 0; kk < FOUT; ++kk) s = fmaf(h[kk] * inv, sWc[kk * FC + j], s);
      v[j] = s;
      ss2 += s * s;
    }
    float inv2 = 1.f / fmaxf(sqrtf(ss2), 1e-12f);
    if (slot == 0) {
#pragma unroll
      for (int j = 0; j < FC; ++j) out[(size_t)i * FC + j] = v[j] * inv2;
    }
  }
}

extern "C" void kernel_launch(void* const* d_in, const int* in_sizes, int n_in,
                              void* d_out, int out_size, void* d_ws, size_t ws_size,
                              hipStream_t stream) {
  const float* x  = (const float*)d_in[0];
  const int*   ei = (const int*)d_in[1];
  const float* W1 = (const float*)d_in[2];
  const float* b1 = (const float*)d_in[3];
  const float* W2 = (const float*)d_in[4];
  const float* b2 = (const float*)d_in[5];
  const float* W3 = (const float*)d_in[6];
  const float* b3 = (const float*)d_in[7];
  const float* Wc = (const float*)d_in[8];
  const float* bc = (const float*)d_in[9];
  float* out = (float*)d_out;

  const int n = NN;
  const int e = NE;
  const int M = 4 * n;        // counters: (dst, src-quarter)
  const int* srcI = ei;       // row 0
  const int* dstI = ei + e;   // row 1

  // Workspace (words):
  //   dinv[N] | ebase[4N+4] | cnt[4N] | cursor[4N] | bsum[256] | adj[E]
  //   | pad->64B | R { p1[3N] | p2[6N] | p3[12N] | accb[12N] }
  // All int arrays 16B-aligned (N%4==0). Total ~= 62.5 MB (<=76 MB proven).
  float* ws = (float*)d_ws;
  float* dinv  = ws;
  int* ebase   = (int*)(ws + n);            // 4N+4 (ebase[4N] = E)
  int* cnt     = ebase + M + 4;
  int* cursor  = cnt + M;
  int* bsum    = cursor + M;                // 256 (196 used)
  int* adj     = bsum + 256;
  size_t roff = (size_t)n + (M + 4) + M + M + 256 + e;
  roff = (roff + 15) & ~(size_t)15;         // round to 16 words = 64B
  float* R     = ws + roff;
  float* p1   = R;                          // 3N
  float* p2   = R + (size_t)3 * n;          // 6N
  float* p3   = R + (size_t)9 * n;          // 12N
  float* accb = R + (size_t)21 * n;         // 12N packed partials

  const int gn  = (n + BK - 1) / BK;
  const int gnS = (n * S + BK - 1) / BK;    // 3125 blocks
  const int gE  = (e + 256 * 8 - 1) / (256 * 8);  // 3125 blocks, 8 edges/thread
  const int NBL = (M + SCT - 1) / SCT;      // 196 scan tiles

  // --- build: hist -> scan -> scatter (counting sort on dst*4 + src/50000) ---
  k_zero<<<(M + 255) / 256, 256, 0, stream>>>(cnt, M);
  k_hist<<<gE, 256, 0, stream>>>(srcI, dstI, cnt, e);
  k_scan1<<<NBL, 256, 0, stream>>>(cnt, bsum, M);
  k_scan2<<<1, 256, 0, stream>>>(bsum, ebase, NBL, M);
  k_scan3<<<NBL, 256, 0, stream>>>(cnt, bsum, ebase, cursor, M);
  k_scatter<<<gE, 256, 0, stream>>>(srcI, dstI, cursor, adj, e);
  k_dinv<<<gn, BK, 0, stream>>>(ebase, dinv, n);

  // --- p1 = dinv * x (12B rows) ---
  k_prep<<<gn, BK, 0, stream>>>(x, dinv, p1, n);

  // --- Layer 1 (p1 = 2.4 MB, fits per-XCD L2): single fused phase ---
  k_gather_fused<3, 6, 0><<<gnS, BK, 0, stream>>>(adj, ebase, p1, W1, b1, dinv, p2, n);

  // --- Layer 2 (p2 = 4.8 MB): 2 phases, halves at quarter boundary 2 ---
  k_gphase<6, true, 0, 2><<<gnS, BK, 0, stream>>>(adj, ebase, p2, accb, n);
  k_gphase_last<6, 12, 1, 2><<<gnS, BK, 0, stream>>>(adj, ebase, p2, W2, b2,
                                                     Wc, bc, dinv, accb, p3, n);

  // --- Layer 3 + classifier (p3 = 9.6 MB): 4 phases over src quarters ---
  k_gphase<12, true, 0, 1><<<gnS, BK, 0, stream>>>(adj, ebase, p3, accb, n);
  k_gphase<12, false, 1, 2><<<gnS, BK, 0, stream>>>(adj, ebase, p3, accb, n);
  k_gphase<12, false, 2, 3><<<gnS, BK, 0, stream>>>(adj, ebase, p3, accb, n);
  k_gphase_last<12, 24, 2, 3><<<gnS, BK, 0, stream>>>(adj, ebase, p3, W3, b3,
                                                      Wc, bc, dinv, accb, out, n);
}

// Round 6
// 453.664 us; speedup vs baseline: 2.2918x; 2.2918x over previous
//
#include <hip/hip_runtime.h>
#include <math.h>

// GCN on MI355X. N=200000 nodes, E=6400000 edges.
// R20: revert R19's direct atomic scatter (WRITE_SIZE 407MB -- 16x line
// amplification from temporally-scattered 4B stores across 8 XCDs; 1040us).
// R14's LDS-binned staging + dense single-block k_build scatter IS the fix
// for that and stays. On top of R18 (461us):
//  (a) k_part CAP 32->24: bin LDS 51.7->39.1KB -> 4 blocks/CU, 32 waves/CU
//      (occ 54%->~100%). k_part was stall-bound with nothing saturated;
//      wave supply is the lever. Overflow residue<=8 + Poisson(5.2) -> ~1e-5
//      fallback rate, negligible. GPART 768->1024.
//  (b) L3 gather: 4 phases -> 3 (cuts at buckets 8/17; slabs 3.15/3.54/3.15MB
//      all < 4MB per-XCD L2). One fewer launch + per-node pass + 19MB acc IO.
// MESSAGES STAY FP32 (R7: bf16 fails 0.21).

static constexpr int NN = 200000;
static constexpr int NE = 6400000;
static constexpr int BK = 256;

static constexpr int SUBW  = 512;                    // nodes per sub-bin (pow2)
static constexpr int NBA   = (NN + SUBW - 1) / SUBW; // 391 sub-bins
static constexpr int CAP   = 24;                     // LDS bin capacity (39.1KB -> 4 blk/CU)
static constexpr int FLUSH = 16;                     // flush granule = 64B
static constexpr int CAPB  = 18400;                  // per-bin staging cap, %16==0
static constexpr int BKP   = 512;                    // k_part block threads
static constexpr int EPT   = 4;                      // edges per thread per chunk
static constexpr int CHUNK = BKP * EPT;              // 2048 edges per chunk
static constexpr int GPART = 1024;                   // 4 blocks/CU
static constexpr int SRCSH = 13;                     // src-bucket shift (8K nodes)
static constexpr int NSB   = (NN + (1 << SRCSH) - 1) >> SRCSH;  // 25 buckets

static constexpr int S     = 4;                      // lanes per node in gathers
static constexpr int LOGS  = 2;

// ---------- pass 1: LDS-binned partition of edges into per-sub-bin staging ----------
__global__ void __launch_bounds__(BKP) k_part(const int* __restrict__ srcI,
                                              const int* __restrict__ dstI,
                                              unsigned* __restrict__ stg,
                                              int* __restrict__ gtail, int e) {
  __shared__ unsigned bin[CAP][NBA];   // [slot][bin]: random-bin writes spread banks
  __shared__ int bcnt[NBA];
  for (int t = threadIdx.x; t < NBA; t += BKP) bcnt[t] = 0;
  __syncthreads();
  int nchunks = (e + CHUNK - 1) / CHUNK;
  for (int c = blockIdx.x; c < nchunks; c += gridDim.x) {
    int base_i = c * CHUNK;
    int dv[EPT], sv[EPT];
#pragma unroll
    for (int u = 0; u < EPT; ++u) {
      int i = base_i + u * BKP + (int)threadIdx.x;
      dv[u] = (i < e) ? __builtin_nontemporal_load(dstI + i) : -1;
      sv[u] = (i < e) ? __builtin_nontemporal_load(srcI + i) : 0;
    }
#pragma unroll
    for (int u = 0; u < EPT; ++u) {
      if (dv[u] >= 0) {
        int b = dv[u] >> 9;
        unsigned rec = ((unsigned)(dv[u] & (SUBW - 1)) << 18) | (unsigned)sv[u];
        int p = atomicAdd(&bcnt[b], 1);
        if (p < CAP) {
          bin[p][b] = rec;
        } else {
          int base = atomicAdd(&gtail[b], 1);               // rare overflow fallback
          stg[(size_t)b * CAPB + base] = rec;
        }
      }
    }
    __syncthreads();
    int b2 = threadIdx.x;                                   // single-pass flush sweep
    if (b2 < NBA) {
      int c2 = bcnt[b2];
      if (c2 > CAP) c2 = CAP;
      if (c2 >= FLUSH) {
        int nfl = c2 & ~(FLUSH - 1);
        int base = atomicAdd(&gtail[b2], nfl);
        size_t o = (size_t)b2 * CAPB + base;
        for (int k = 0; k < nfl; k += 4) {
          uint4 v;
          v.x = bin[k][b2]; v.y = bin[k + 1][b2]; v.z = bin[k + 2][b2]; v.w = bin[k + 3][b2];
          *(uint4*)(stg + o + k) = v;                       // base%16==0 -> aligned
        }
        int r = c2 - nfl;
        for (int k = 0; k < r; ++k) bin[k][b2] = bin[nfl + k][b2];
        bcnt[b2] = r;
      }
    }
    __syncthreads();
  }
  int b2 = threadIdx.x;                                     // final residual flush
  if (b2 < NBA) {
    int c2 = bcnt[b2];
    if (c2 > CAP) c2 = CAP;
    if (c2 > 0) {
      int base = atomicAdd(&gtail[b2], c2);
      size_t o = (size_t)b2 * CAPB + base;
      for (int k = 0; k < c2; ++k) stg[o + k] = bin[k][b2];
    }
  }
}

// ---------- exclusive scan over sub-bin sizes (single block, 512 thr) ----------
__global__ void k_scan_sub(const int* __restrict__ gtail, int* __restrict__ sbase) {
  __shared__ int s0[512], s1[512];
  int t = threadIdx.x;
  int v = (t < NBA) ? gtail[t] : 0;
  s0[t] = v;
  __syncthreads();
  int* a = s0; int* b = s1;
  for (int off = 1; off < 512; off <<= 1) {
    int x = a[t] + ((t >= off) ? a[t - off] : 0);
    b[t] = x;
    __syncthreads();
    int* tmp = a; a = b; b = tmp;
  }
  if (t < NBA) sbase[t] = a[t] - v;  // exclusive
}

// ---------- pass 2: 2-D hist + scans + ONE ordered scatter -> rowptr, adj ----------
// Also emits per-dst boundary pointers b8/b13/b17 (first edge with src-bucket
// >= 8/13/17) straight from the exclusive histogram.
__global__ void __launch_bounds__(BK) k_build(const unsigned* __restrict__ stg,
                                              const int* __restrict__ gtail,
                                              const int* __restrict__ sbase,
                                              int* __restrict__ rowptr,
                                              int* __restrict__ adj,
                                              int* __restrict__ b8,
                                              int* __restrict__ b13,
                                              int* __restrict__ b17) {
  __shared__ unsigned hist2[SUBW * NSB];   // 51.2 KB: [dl][sb] counts -> offsets
  __shared__ int htot[SUBW];               // per-dl total
  __shared__ int s0[SUBW], s1[SUBW];
  int b = blockIdx.x;
  int m = gtail[b]; if (m > CAPB) m = CAPB;
  size_t off = (size_t)b * CAPB;
  int base = sbase[b];
  if (b == NBA - 1 && threadIdx.x == 0) rowptr[NN] = base + m;  // dense total
  for (int t = threadIdx.x; t < SUBW * NSB; t += BK) hist2[t] = 0;
  __syncthreads();
  // read 1: 2-D histogram
  for (int k = threadIdx.x; k < m; k += BK) {
    unsigned rec = stg[off + k];
    int dl = rec >> 18;
    int sb = (int)((rec & 0x3FFFFu) >> SRCSH);
    atomicAdd(&hist2[dl * NSB + sb], 1u);
  }
  __syncthreads();
  // per-dl serial exclusive scan over sb (dl stride 25 is odd -> banks spread)
  for (int dl = threadIdx.x; dl < SUBW; dl += BK) {
    unsigned run = 0;
    for (int sb = 0; sb < NSB; ++sb) {
      unsigned c = hist2[dl * NSB + sb];
      hist2[dl * NSB + sb] = run;
      run += c;
    }
    htot[dl] = (int)run;
    s0[dl] = (int)run;
  }
  __syncthreads();
  // block inclusive scan over 512 dls (ping-pong)
  int* a = s0; int* bb = s1;
  for (int o2 = 1; o2 < SUBW; o2 <<= 1) {
    for (int t = threadIdx.x; t < SUBW; t += BK) bb[t] = a[t] + ((t >= o2) ? a[t - o2] : 0);
    __syncthreads();
    int* tmp = a; a = bb; bb = tmp;
  }
  for (int t = threadIdx.x; t < SUBW; t += BK) {
    int node = b * SUBW + t;
    int ex = a[t] - htot[t];
    if (node < NN) {
      rowptr[node] = base + ex;
      b8[node]  = base + ex + (int)hist2[t * NSB + 8];   // hist2 = exclusive prefix here
      b13[node] = base + ex + (int)hist2[t * NSB + 13];
      b17[node] = base + ex + (int)hist2[t * NSB + 17];
    }
    bb[t] = ex;  // dst-base offsets live in the free scan buffer
  }
  __syncthreads();
  // read 2: single ordered scatter. pos = ex[dl] + off2d[dl][sb] + arrival.
  for (int k = threadIdx.x; k < m; k += BK) {
    unsigned rec = stg[off + k];
    int dl = rec >> 18;
    unsigned src = rec & 0x3FFFFu;
    int sb = (int)(src >> SRCSH);
    int p = bb[dl] + (int)atomicAdd(&hist2[dl * NSB + sb], 1u);
    adj[base + p] = (int)src;          // single-block 64KB region, written once
  }
}

__global__ void k_zero(int* __restrict__ p, int n) {
  int i = blockIdx.x * blockDim.x + threadIdx.x;
  if (i < n) p[i] = 0;
}

// counts = rowptr diff (dense packing from counting sort)
__global__ void k_dinv(const int* __restrict__ rowptr, float* __restrict__ dinv, int n) {
  int i = blockIdx.x * blockDim.x + threadIdx.x;
  if (i < n) dinv[i] = rsqrtf(1.0f + (float)(rowptr[i + 1] - rowptr[i]));
}

// p1[i] = dinv[i] * x[i]  (3 floats, packed 12B rows)
__global__ void k_prep(const float* __restrict__ x, const float* __restrict__ dinv,
                       float* __restrict__ p1, int n) {
  int i = blockIdx.x * blockDim.x + threadIdx.x;
  if (i >= n) return;
  float di = dinv[i];
  float3 v;
  v.x = di * x[3 * (size_t)i];
  v.y = di * x[3 * (size_t)i + 1];
  v.z = di * x[3 * (size_t)i + 2];
  *(float3*)(p1 + 3 * (size_t)i) = v;
}

// ---------- packed-row load/accumulate/store (RW floats per row) ----------
template <int RW> struct RowT;
template <> struct RowT<3> {
  using T = float3;   // 12B rows
  static __device__ inline T ld(const float* __restrict__ p) { return *(const float3*)p; }
  static __device__ inline void add(float* __restrict__ a, const T& v) {
    a[0] += v.x; a[1] += v.y; a[2] += v.z;
  }
  static __device__ inline void st(float* __restrict__ p, const float* __restrict__ a) {
    *(float3*)p = make_float3(a[0], a[1], a[2]);
  }
};
template <> struct RowT<6> {
  struct T { float2 a, b, c; };       // 24B rows, 8B-aligned
  static __device__ inline T ld(const float* __restrict__ p) {
    T t; t.a = *(const float2*)p; t.b = *(const float2*)(p + 2); t.c = *(const float2*)(p + 4);
    return t;
  }
  static __device__ inline void add(float* __restrict__ a, const T& v) {
    a[0] += v.a.x; a[1] += v.a.y; a[2] += v.b.x; a[3] += v.b.y; a[4] += v.c.x; a[5] += v.c.y;
  }
  static __device__ inline void st(float* __restrict__ p, const float* __restrict__ a) {
    *(float2*)(p)     = make_float2(a[0], a[1]);
    *(float2*)(p + 2) = make_float2(a[2], a[3]);
    *(float2*)(p + 4) = make_float2(a[4], a[5]);
  }
};
template <> struct RowT<12> {
  struct T { float4 a, b, c; };       // 48B rows, 16B-aligned bases
  static __device__ inline T ld(const float* __restrict__ p) {
    T t; t.a = *(const float4*)p; t.b = *(const float4*)(p + 4); t.c = *(const float4*)(p + 8);
    return t;
  }
  static __device__ inline void add(float* __restrict__ a, const T& v) {
    a[0] += v.a.x; a[1] += v.a.y; a[2] += v.a.z; a[3] += v.a.w;
    a[4] += v.b.x; a[5] += v.b.y; a[6] += v.b.z; a[7] += v.b.w;
    a[8] += v.c.x; a[9] += v.c.y; a[10] += v.c.z; a[11] += v.c.w;
  }
  static __device__ inline void st(float* __restrict__ p, const float* __restrict__ a) {
    *(float4*)(p)     = make_float4(a[0], a[1], a[2], a[3]);
    *(float4*)(p + 4) = make_float4(a[4], a[5], a[6], a[7]);
    *(float4*)(p + 8) = make_float4(a[8], a[9], a[10], a[11]);
  }
};

// ---------- slot-strided gather over [st,en), unroll UN, adj prefetch 1 ahead ----------
template <int RW, int UN>
__device__ inline void gather_p(const int* __restrict__ adj, int st, int en,
                                const float* __restrict__ pin, float* __restrict__ acc,
                                int slot) {
  using RT = RowT<RW>;
  using T = typename RT::T;
  int k = st + slot;
  if (k + (UN - 1) * S < en) {
    int a[UN];
#pragma unroll
    for (int u = 0; u < UN; ++u) a[u] = adj[k + u * S];
    for (;;) {
      int kn = k + UN * S;
      bool more = (kn + (UN - 1) * S < en);
      int b[UN];
#pragma unroll
      for (int u = 0; u < UN; ++u) b[u] = 0;
      if (more) {
#pragma unroll
        for (int u = 0; u < UN; ++u) b[u] = adj[kn + u * S];
      }
      T v[UN];
#pragma unroll
      for (int u = 0; u < UN; ++u) v[u] = RT::ld(pin + (size_t)a[u] * RW);
#pragma unroll
      for (int u = 0; u < UN; ++u) RT::add(acc, v[u]);
      k = kn;
      if (!more) break;
#pragma unroll
      for (int u = 0; u < UN; ++u) a[u] = b[u];
    }
  }
  for (; k < en; k += S) {
    T v = RT::ld(pin + (size_t)adj[k] * RW);
    RT::add(acc, v);
  }
}

// 4-lane butterfly: all lanes end with the full sum
template <int FIN>
__device__ inline void group_reduce(float* __restrict__ acc) {
#pragma unroll
  for (int j = 0; j < FIN; ++j) {
    acc[j] += __shfl_xor(acc[j], 1);
    acc[j] += __shfl_xor(acc[j], 2);
  }
}

// ---------- single-phase fused gather (layer 1 only; slab fits L2) ----------
template <int RW, int FOUT, int MODE>
__global__ void __launch_bounds__(BK, 8) k_gather_fused(
    const int* __restrict__ adj, const int* __restrict__ rowptr,
    const float* __restrict__ pin, const float* __restrict__ W,
    const float* __restrict__ bias, const float* __restrict__ dinv,
    float* __restrict__ pout, int n) {
  __shared__ float sW[RW * FOUT];
  __shared__ float sb[FOUT];
  for (int t = threadIdx.x; t < RW * FOUT; t += BK) sW[t] = W[t];
  if (threadIdx.x < FOUT) sb[threadIdx.x] = bias[threadIdx.x];
  __syncthreads();
  int g = blockIdx.x * blockDim.x + threadIdx.x;
  int i = g >> LOGS;
  int slot = g & (S - 1);
  if (i >= n) return;
  float acc[RW] = {};
  if (slot == 0) {                                  // self-loop on slot 0
    typename RowT<RW>::T v = RowT<RW>::ld(pin + (size_t)i * RW);
    RowT<RW>::add(acc, v);
  }
  gather_p<RW, 4>(adj, rowptr[i], rowptr[i + 1], pin, acc, slot);
  group_reduce<RW>(acc);
  float di = dinv[i];
  float h[FOUT];
  float ss = 0.f;
#pragma unroll
  for (int j = 0; j < FOUT; ++j) {
    float s = 0.f;
#pragma unroll
    for (int kk = 0; kk < RW; ++kk) s = fmaf(acc[kk], sW[kk * FOUT + j], s);
    float t = fmaf(di, s, sb[j]);
    h[j] = t;
    ss += t * t;
  }
  float o[FOUT];
  if (MODE == 0) {
#pragma unroll
    for (int j = 0; j < FOUT; ++j) o[j] = di * tanhf(h[j]);
  } else {
    float inv = 1.f / fmaxf(sqrtf(ss), 1e-12f);
#pragma unroll
    for (int j = 0; j < FOUT; ++j) o[j] = di * tanhf(h[j] * inv);
  }
  if (slot == 0) {
    float* po = pout + (size_t)i * FOUT;
    if (MODE == 0) {                                 // 24B rows: 3x float2
      *(float2*)(po)     = make_float2(o[0], o[1]);
      *(float2*)(po + 2) = make_float2(o[2], o[3]);
      *(float2*)(po + 4) = make_float2(o[4], o[5]);
    } else {                                         // 48B rows: 3x float4
      *(float4*)(po)     = make_float4(o[0], o[1], o[2], o[3]);
      *(float4*)(po + 4) = make_float4(o[4], o[5], o[6], o[7]);
      *(float4*)(po + 8) = make_float4(o[8], o[9], o[10], o[11]);
    }
  }
}

// ---------- phased gather: one src-range slab per kernel launch ----------
// FIRST: acc = self-loop; else acc = reload packed partial (slot 0 holds it).
template <int RW, bool FIRST>
__global__ void __launch_bounds__(BK, 8) k_gphase(
    const int* __restrict__ adj, const int* __restrict__ stA,
    const int* __restrict__ enB, const float* __restrict__ pin,
    float* __restrict__ accb, int n) {
  int g = blockIdx.x * blockDim.x + threadIdx.x;
  int i = g >> LOGS;
  int slot = g & (S - 1);
  if (i >= n) return;
  float acc[RW] = {};
  if (slot == 0) {
    if (FIRST) {
      typename RowT<RW>::T v = RowT<RW>::ld(pin + (size_t)i * RW);  // self-loop
      RowT<RW>::add(acc, v);
    } else {
      typename RowT<RW>::T v = RowT<RW>::ld(accb + (size_t)i * RW); // partial
      RowT<RW>::add(acc, v);
    }
  }
  gather_p<RW, 2>(adj, stA[i], enB[i], pin, acc, slot);
  group_reduce<RW>(acc);
  if (slot == 0) RowT<RW>::st(accb + (size_t)i * RW, acc);
}

// ---------- final phase: last slab + epilogue ----------
// MODE 1: l2norm+tanh -> pout (48B rows for FOUT=12)
// MODE 2: l2norm -> Wc -> l2norm -> out (13 floats)
template <int RW, int FOUT, int MODE>
__global__ void __launch_bounds__(BK, 6) k_gphase_last(
    const int* __restrict__ adj, const int* __restrict__ stA,
    const int* __restrict__ rowptr, const float* __restrict__ pin,
    const float* __restrict__ W, const float* __restrict__ bias,
    const float* __restrict__ Wc, const float* __restrict__ bc,
    const float* __restrict__ dinv, const float* __restrict__ accb,
    float* __restrict__ out, int n) {
  constexpr int FC = 13;
  __shared__ float sW[RW * FOUT];
  __shared__ float sb[FOUT];
  __shared__ float sWc[MODE == 2 ? FOUT * FC : 1];
  __shared__ float sbc[MODE == 2 ? FC : 1];
  for (int t = threadIdx.x; t < RW * FOUT; t += BK) sW[t] = W[t];
  if (threadIdx.x < FOUT) sb[threadIdx.x] = bias[threadIdx.x];
  if (MODE == 2) {
    for (int t = threadIdx.x; t < FOUT * FC; t += BK) sWc[t] = Wc[t];
    if (threadIdx.x < FC) sbc[threadIdx.x] = bc[threadIdx.x];
  }
  __syncthreads();
  int g = blockIdx.x * blockDim.x + threadIdx.x;
  int i = g >> LOGS;
  int slot = g & (S - 1);
  if (i >= n) return;
  float acc[RW] = {};
  if (slot == 0) {
    typename RowT<RW>::T v = RowT<RW>::ld(accb + (size_t)i * RW);   // partial
    RowT<RW>::add(acc, v);
  }
  gather_p<RW, 2>(adj, stA[i], rowptr[i + 1], pin, acc, slot);
  group_reduce<RW>(acc);
  float di = dinv[i];
  float h[FOUT];
  float ss = 0.f;
#pragma unroll
  for (int j = 0; j < FOUT; ++j) {
    float s = 0.f;
#pragma unroll
    for (int kk = 0; kk < RW; ++kk) s = fmaf(acc[kk], sW[kk * FOUT + j], s);
    float t = fmaf(di, s, sb[j]);
    h[j] = t;
    ss += t * t;
  }
  float inv = 1.f / fmaxf(sqrtf(ss), 1e-12f);
  if (MODE == 1) {
    float o[FOUT];
#pragma unroll
    for (int j = 0; j < FOUT; ++j) o[j] = di * tanhf(h[j] * inv);
    if (slot == 0) {
      float* po = out + (size_t)i * FOUT;                  // 48B rows (FOUT=12)
      *(float4*)(po)     = make_float4(o[0], o[1], o[2], o[3]);
      *(float4*)(po + 4) = make_float4(o[4], o[5], o[6], o[7]);
      *(float4*)(po + 8) = make_float4(o[8], o[9], o[10], o[11]);
    }
  } else {
    float v[FC];
    float ss2 = 0.f;
#pragma unroll
    for (int j = 0; j < FC; ++j) {
      float s = sbc[j];
#pragma unroll
      for (int kk = 0; kk < FOUT; ++kk) s = fmaf(h[kk] * inv, sWc[kk * FC + j], s);
      v[j] = s;
      ss2 += s * s;
    }
    float inv2 = 1.f / fmaxf(sqrtf(ss2), 1e-12f);
    if (slot == 0) {
#pragma unroll
      for (int j = 0; j < FC; ++j) out[(size_t)i * FC + j] = v[j] * inv2;
    }
  }
}

extern "C" void kernel_launch(void* const* d_in, const int* in_sizes, int n_in,
                              void* d_out, int out_size, void* d_ws, size_t ws_size,
                              hipStream_t stream) {
  const float* x  = (const float*)d_in[0];
  const int*   ei = (const int*)d_in[1];
  const float* W1 = (const float*)d_in[2];
  const float* b1 = (const float*)d_in[3];
  const float* W2 = (const float*)d_in[4];
  const float* b2 = (const float*)d_in[5];
  const float* W3 = (const float*)d_in[6];
  const float* b3 = (const float*)d_in[7];
  const float* Wc = (const float*)d_in[8];
  const float* bc = (const float*)d_in[9];
  float* out = (float*)d_out;

  const int n = NN;
  const int e = NE;
  const int* srcI = ei;       // row 0
  const int* dstI = ei + e;   // row 1

  // Workspace (words):
  //   dinv[N] | rowptr[N+8] | gtail[512] | sbase[512] | adj[E] | b8[N] | b13[N]
  //   | b17[N] | pad->64B | R
  // R hosts stg[NBA*CAPB]=7.20M words during build, then
  //   p1[3N] | p2[6N] | p3[12N] | accb[12N]  (=6.6M words) during gathers.
  // Total ~= 66 MB (R8 proved >= 76 MB safe).
  float* ws = (float*)d_ws;
  float* dinv  = ws;
  int* rowptr  = (int*)(ws + n);            // N+8 (uses N+1, padded)
  int* gtail   = rowptr + n + 8;
  int* sbase   = gtail + 512;
  int* adj     = sbase + 512;
  int* b8      = adj + e;
  int* b13     = b8 + n;
  int* b17     = b13 + n;
  size_t roff = (size_t)n + (n + 8) + 512 + 512 + e + 3 * (size_t)n;
  roff = (roff + 15) & ~(size_t)15;         // round to 16 words = 64B
  float* R     = ws + roff;
  unsigned* stg = (unsigned*)R;
  float* p1   = R;                          // 3N
  float* p2   = R + (size_t)3 * n;          // 6N
  float* p3   = R + (size_t)9 * n;          // 12N
  float* accb = R + (size_t)21 * n;         // 12N packed partials (16B-aligned)

  const int gn  = (n + BK - 1) / BK;
  const int gnS = (n * S + BK - 1) / BK;    // 3125 blocks

  // --- CSR build via binned counting sort, 2-D-hist-ordered scatter ---
  k_zero<<<2, BK, 0, stream>>>(gtail, 512);
  k_part<<<GPART, BKP, 0, stream>>>(srcI, dstI, stg, gtail, e);
  k_scan_sub<<<1, 512, 0, stream>>>(gtail, sbase);
  k_build<<<NBA, BK, 0, stream>>>(stg, gtail, sbase, rowptr, adj, b8, b13, b17);
  k_dinv<<<gn, BK, 0, stream>>>(rowptr, dinv, n);

  // --- p1 = dinv * x (12B rows) ---
  k_prep<<<gn, BK, 0, stream>>>(x, dinv, p1, n);

  // --- Layer 1 (p1 = 2.4 MB, fits per-XCD L2): single fused phase ---
  k_gather_fused<3, 6, 0><<<gnS, BK, 0, stream>>>(adj, rowptr, p1, W1, b1, dinv, p2, n);

  // --- Layer 2 (p2 = 4.8 MB): 2 phases, cut at bucket 13 ---
  k_gphase<6, true><<<gnS, BK, 0, stream>>>(adj, rowptr, b13, p2, accb, n);
  k_gphase_last<6, 12, 1><<<gnS, BK, 0, stream>>>(adj, b13, rowptr, p2, W2, b2,
                                                  Wc, bc, dinv, accb, p3, n);

  // --- Layer 3 + classifier (p3 = 9.6 MB): 3 phases, cuts at buckets 8/17 ---
  k_gphase<12, true><<<gnS, BK, 0, stream>>>(adj, rowptr, b8, p3, accb, n);
  k_gphase<12, false><<<gnS, BK, 0, stream>>>(adj, b8, b17, p3, accb, n);
  k_gphase_last<12, 24, 2><<<gnS, BK, 0, stream>>>(adj, b17, rowptr, p3, W3, b3,
                                                   Wc, bc, dinv, accb, out, n);
}